// Round 4
// baseline (1920.212 us; speedup 1.0000x reference)
//
#include <hip/hip_runtime.h>

#define D_   64
#define NBT_ 12800   // B*T = 32*400
#define B_   32

typedef float v4f __attribute__((ext_vector_type(4)));

// Broadcast lane l's value of v to all lanes (SGPR result).
__device__ __forceinline__ float rl(float v, int l) {
    return __uint_as_float(__builtin_amdgcn_readlane(__float_as_uint(v), l));
}

// One wave (64 lanes) per (b,t) matrix. Lane i holds row i of sigma in 64
// VGPRs (plain float[64]; ext-vector arrays spilled in round 2).
//
// Round-3 counters proved this kernel is LDS-PIPE-throughput bound:
// ~528 uniform-address ds_read_b128 x ~12cyc = 6.7k LDS cycles/wave;
// 50 waves/CU -> ~95% of the per-CU LDS pipe (VALU only 26%, HBM 9%).
// Broadcast volume is already minimal (each L[j][k] read once at b128
// width), so the fix is PIPE BALANCING, not fewer bytes:
//   - the 3 chunks (12 columns) nearest the diagonal are updated via
//     v_readlane broadcasts (VALU pipe) -> LDS reads drop ~33%, and the
//     serial dependency row[k]->a->row[k+1] becomes VALU-only (no LDS
//     round-trip latency on the critical chain).
//   - remaining far chunks use the LDS uniform-address v4f broadcast
//     (conflict-free, measured 0 conflicts; validated in-wave DS
//     write->read ordering).
// Dead columns (j <= k) in the boundary chunk are skipped at compile time.
// Code size ~25 KB: stays inside the 32 KB L1I (round-0 readlane-only
// version at ~38 KB thrashed I$).
__global__ __launch_bounds__(256) void chol_ll(const float* __restrict__ x,
                                               const float* __restrict__ mu,
                                               const float* __restrict__ sigma,
                                               float* __restrict__ partial) {
    const int lane = threadIdx.x & 63;
    const int wv   = threadIdx.x >> 6;
    const int bt   = blockIdx.x * 4 + wv;

    __shared__ __align__(16) float colbuf[4][2][D_];   // per-wave dbuf column
    float* const cb0 = colbuf[wv][0];
    float* const cb1 = colbuf[wv][1];

    const float4* srow = (const float4*)(sigma + (size_t)bt * (D_ * D_) + (size_t)lane * D_);
    float row[D_];
    #pragma unroll
    for (int m = 0; m < D_ / 4; ++m) {
        float4 t = srow[m];
        row[4 * m + 0] = t.x; row[4 * m + 1] = t.y;
        row[4 * m + 2] = t.z; row[4 * m + 3] = t.w;
    }
    float d = x[bt * D_ + lane] - mu[bt * D_ + lane];

    float q = 0.f, lg = 0.f;
    #pragma unroll
    for (int k = 0; k < D_; ++k) {
        // diagonal (lane k's row[k] is valid) + EPS regularization
        float s   = rl(row[k], k) + 1e-6f;
        float inv = __builtin_amdgcn_rsqf(s);   // 1/L[k][k]
        lg += __builtin_amdgcn_logf(s);         // log2(s); scaled at end
        float a = row[k] * inv;                 // L[i][k] for lanes i >= k
        // fused forward substitution: z_k = d_k / L[k][k]
        float zk = rl(d, k) * inv;
        q += zk * zk;
        d -= a * zk;                            // valid for lanes i > k

        if (k < D_ - 1) {
            const int m0 = (k + 1) >> 2;            // first live chunk
            const int ms = (m0 + 3 < D_ / 4) ? m0 + 3 : D_ / 4;  // pipe split

            // far chunks via LDS: write scaled column (dbuf slot) first
            if (ms < D_ / 4) {
                float* cb = (k & 1) ? cb1 : cb0;
                cb[lane] = a;
            }

            // near chunks via readlane (VALU pipe); j<=k dead -> skipped
            #pragma unroll
            for (int m = m0; m < ms; ++m) {
                #pragma unroll
                for (int e = 0; e < 4; ++e) {
                    const int j = 4 * m + e;
                    if (j > k) row[j] -= a * rl(a, j);
                }
            }

            // far chunks via LDS uniform-address broadcast (LDS pipe)
            if (ms < D_ / 4) {
                float* cb = (k & 1) ? cb1 : cb0;
                #pragma unroll
                for (int m = ms; m < D_ / 4; ++m) {
                    v4f bc = *(const v4f*)(cb + 4 * m);
                    row[4 * m + 0] -= a * bc[0];
                    row[4 * m + 1] -= a * bc[1];
                    row[4 * m + 2] -= a * bc[2];
                    row[4 * m + 3] -= a * bc[3];
                }
            }
        }
    }

    if (lane == 0) {
        float log_det = 0.34657359027997264f * lg;      // 0.5 * ln(2) * sum(log2 s)
        // -0.5*sum(z^2) - log_det - 0.5*D*ln(2*pi)
        float lp = -0.5f * q - log_det - 58.81206612509905f;
        partial[bt] = lp;
    }
}

__global__ __launch_bounds__(1024) void reduce_ll(const float* __restrict__ partial,
                                                  float* __restrict__ out) {
    float s = 0.f;
    for (int i = threadIdx.x; i < NBT_; i += 1024) s += partial[i];
    #pragma unroll
    for (int off = 32; off > 0; off >>= 1) s += __shfl_down(s, off, 64);
    __shared__ float ws[16];
    const int lane = threadIdx.x & 63, w = threadIdx.x >> 6;
    if (lane == 0) ws[w] = s;
    __syncthreads();
    if (threadIdx.x == 0) {
        float t = 0.f;
        #pragma unroll
        for (int i = 0; i < 16; ++i) t += ws[i];
        out[0] = -t / (float)B_;   // out = -mean_b sum_t log_prob
    }
}

extern "C" void kernel_launch(void* const* d_in, const int* in_sizes, int n_in,
                              void* d_out, int out_size, void* d_ws, size_t ws_size,
                              hipStream_t stream) {
    const float* x     = (const float*)d_in[0];
    const float* mu    = (const float*)d_in[1];
    const float* sigma = (const float*)d_in[2];
    float* partial = (float*)d_ws;   // NBT_ floats = 51.2 KB scratch
    chol_ll<<<NBT_ / 4, 256, 0, stream>>>(x, mu, sigma, partial);
    reduce_ll<<<1, 1024, 0, stream>>>(partial, (float*)d_out);
}

// Round 5
// 332.107 us; speedup vs baseline: 5.7819x; 5.7819x over previous
//
#include <hip/hip_runtime.h>

#define D_   64
#define NBT_ 12800   // B*T = 32*400
#define B_   32

typedef float v4f __attribute__((ext_vector_type(4)));

// Broadcast lane l's value of v to all lanes (SGPR result).
__device__ __forceinline__ float rl(float v, int l) {
    return __uint_as_float(__builtin_amdgcn_readlane(__float_as_uint(v), l));
}

// One wave (64 lanes) per (b,t) matrix. Lane i holds row i of sigma in 64
// VGPRs (plain float[64]).
//
// Round-3 counters: pure-LDS broadcast version is LDS-PIPE bound (~95% of
// the per-CU LDS pipe; VALU 26%). The LDS pipe is 1/CU while VALU is 4/CU
// (per-SIMD), so broadcast work moved to v_readlane is a 4x-wider pipe.
// Hybrid split per iteration k:
//   - near 3 chunks (12 columns) after the diagonal: v_readlane broadcast
//     (VALU pipe). Also removes the LDS write->read round-trip from the
//     serial critical chain (row[k+1..] updated VALU-only).
//   - far chunks: LDS uniform-address v4f broadcast (conflict-free,
//     0 conflicts measured; in-wave DS write->read ordering validated).
// LDS reads/wave: 528 -> 351 => ~4.6k LDS cyc/wave => ~230k cyc/CU.
//
// Round-4 attempt of this split spilled row[] to scratch (VGPR=104,
// WRITE_SIZE=4.5 GB): allocator chased occupancy. Fix here:
// __launch_bounds__(256, 2) explicitly allows ~256 VGPR/lane so the
// ~150-reg live set fits. 8 waves/CU is plenty for an LDS-bound kernel.
//
// Dead-column updates (j <= k in near chunks / boundary far chunk) read
// and write only dead registers and dead lanes' a; garbage never reaches
// the diagonal, z, q, lg (all sourced from lane >= k broadcasts).
__global__ __launch_bounds__(256, 2) void chol_ll(const float* __restrict__ x,
                                                  const float* __restrict__ mu,
                                                  const float* __restrict__ sigma,
                                                  float* __restrict__ partial) {
    const int lane = threadIdx.x & 63;
    const int wv   = threadIdx.x >> 6;
    const int bt   = blockIdx.x * 4 + wv;

    __shared__ __align__(16) float colbuf[4][2][D_];   // per-wave dbuf column
    float* const cb0 = colbuf[wv][0];
    float* const cb1 = colbuf[wv][1];

    const float4* srow = (const float4*)(sigma + (size_t)bt * (D_ * D_) + (size_t)lane * D_);
    float row[D_];
    #pragma unroll
    for (int m = 0; m < D_ / 4; ++m) {
        float4 t = srow[m];
        row[4 * m + 0] = t.x; row[4 * m + 1] = t.y;
        row[4 * m + 2] = t.z; row[4 * m + 3] = t.w;
    }
    float d = x[bt * D_ + lane] - mu[bt * D_ + lane];

    float q = 0.f, lg = 0.f;
    #pragma unroll
    for (int k = 0; k < D_; ++k) {
        // diagonal (lane k's row[k] is valid) + EPS regularization
        float s   = rl(row[k], k) + 1e-6f;
        float inv = __builtin_amdgcn_rsqf(s);   // 1/L[k][k]
        lg += __builtin_amdgcn_logf(s);         // log2(s); scaled at end
        float a = row[k] * inv;                 // L[i][k] for lanes i >= k
        // fused forward substitution: z_k = d_k / L[k][k]
        float zk = rl(d, k) * inv;
        q += zk * zk;
        d -= a * zk;                            // valid for lanes i > k

        if (k < D_ - 1) {
            // broadcast scaled column k via LDS (double-buffered slot);
            // unconditional to keep per-iteration code uniform.
            float* cb = (k & 1) ? cb1 : cb0;
            cb[lane] = a;

            const int m0 = (k + 1) >> 2;                          // first live chunk
            const int ms = (m0 + 3 < D_ / 4) ? m0 + 3 : D_ / 4;   // pipe split

            // near chunks via readlane (VALU pipe); dead j <= k harmless
            #pragma unroll
            for (int m = m0; m < ms; ++m) {
                row[4 * m + 0] -= a * rl(a, 4 * m + 0);
                row[4 * m + 1] -= a * rl(a, 4 * m + 1);
                row[4 * m + 2] -= a * rl(a, 4 * m + 2);
                row[4 * m + 3] -= a * rl(a, 4 * m + 3);
            }

            // far chunks via LDS uniform-address broadcast (LDS pipe)
            #pragma unroll
            for (int m = ms; m < D_ / 4; ++m) {
                v4f bc = *(const v4f*)(cb + 4 * m);
                row[4 * m + 0] -= a * bc[0];
                row[4 * m + 1] -= a * bc[1];
                row[4 * m + 2] -= a * bc[2];
                row[4 * m + 3] -= a * bc[3];
            }
        }
    }

    if (lane == 0) {
        float log_det = 0.34657359027997264f * lg;      // 0.5 * ln(2) * sum(log2 s)
        // -0.5*sum(z^2) - log_det - 0.5*D*ln(2*pi)
        float lp = -0.5f * q - log_det - 58.81206612509905f;
        partial[bt] = lp;
    }
}

__global__ __launch_bounds__(1024) void reduce_ll(const float* __restrict__ partial,
                                                  float* __restrict__ out) {
    float s = 0.f;
    for (int i = threadIdx.x; i < NBT_; i += 1024) s += partial[i];
    #pragma unroll
    for (int off = 32; off > 0; off >>= 1) s += __shfl_down(s, off, 64);
    __shared__ float ws[16];
    const int lane = threadIdx.x & 63, w = threadIdx.x >> 6;
    if (lane == 0) ws[w] = s;
    __syncthreads();
    if (threadIdx.x == 0) {
        float t = 0.f;
        #pragma unroll
        for (int i = 0; i < 16; ++i) t += ws[i];
        out[0] = -t / (float)B_;   // out = -mean_b sum_t log_prob
    }
}

extern "C" void kernel_launch(void* const* d_in, const int* in_sizes, int n_in,
                              void* d_out, int out_size, void* d_ws, size_t ws_size,
                              hipStream_t stream) {
    const float* x     = (const float*)d_in[0];
    const float* mu    = (const float*)d_in[1];
    const float* sigma = (const float*)d_in[2];
    float* partial = (float*)d_ws;   // NBT_ floats = 51.2 KB scratch
    chol_ll<<<NBT_ / 4, 256, 0, stream>>>(x, mu, sigma, partial);
    reduce_ll<<<1, 1024, 0, stream>>>(partial, (float*)d_out);
}

// Round 6
// 312.244 us; speedup vs baseline: 6.1497x; 1.0636x over previous
//
#include <hip/hip_runtime.h>

#define D_   64
#define NBT_ 12800   // B*T = 32*400
#define B_   32

typedef float v4f __attribute__((ext_vector_type(4)));

// Broadcast lane l's value of v to all lanes (SGPR result).
__device__ __forceinline__ float rl(float v, int l) {
    return __uint_as_float(__builtin_amdgcn_readlane(__float_as_uint(v), l));
}

// One wave (64 lanes) per (b,t) matrix. Lane i holds row i of sigma in 64
// VGPRs (plain float[64]; scalar — ext-vector ARRAYS spilled in round 2).
//
// Rounds 3/5 established the regime: NOT pipe-bound (r5: VALU 55%, LDS
// <=75%) but ROUND-TRIP LATENCY bound — 63 rank-1 iterations each expose
// readlane->rsqrt->ds_write->ds_read(~120cy)->FMA serially, and ~2-4
// waves/SIMD can't hide 63 exposures (wave duty cycle ~15-25%).
// Calibrated from r3->r5 deltas: v_readlane ~8 cyc effective.
//
// Fix: RANK-4 BLOCKED right-looking Cholesky. Panel g = columns 4g..4g+3
// (exactly chunk g). Per group:
//   1. factor the 4 panel columns via readlane only (6 intra-panel FMAs +
//      diagonals; short serial section), fusing forward-substitution z,
//      q and log-det as before;
//   2. ONE ds_write_b128/lane publishes the 4 scaled columns;
//   3. per trailing column j: ONE uniform-address ds_read_b128 yields all
//      4 broadcasts L[j][k0..k0+3] -> 4 FMAs.
// LDS round-trips 63 -> 16, readlanes ~834 -> ~350, 4x FMA work per
// exposed latency. Code ~3.4k instr ~20 KB (< 32 KB L1I).
//
// Double-buffered LDS block (parity g&1) removes cross-group WAR; same-
// iteration in-wave ds_write->ds_read ordering validated on HW (r2/r3/r5
// all passed, absmax 0.0). Dead lanes/columns (i<k or j<=k) carry garbage
// through registers that are never read via a live broadcast path.
//
// __launch_bounds__(256, 2): validated anti-spill setting (r4 spilled
// 4.5 GB without it; r5 clean at VGPR=100 with it).
__global__ __launch_bounds__(256, 2) void chol_ll(const float* __restrict__ x,
                                                  const float* __restrict__ mu,
                                                  const float* __restrict__ sigma,
                                                  float* __restrict__ partial) {
    const int lane = threadIdx.x & 63;
    const int wv   = threadIdx.x >> 6;
    const int bt   = blockIdx.x * 4 + wv;

    // [wave][parity][lane*4 + p] : 4 KB buffers x2 parity x4 waves = 8 KB
    __shared__ __align__(16) float colbuf[4][2][4 * D_];
    float* const cb0 = colbuf[wv][0];
    float* const cb1 = colbuf[wv][1];

    const float4* srow = (const float4*)(sigma + (size_t)bt * (D_ * D_) + (size_t)lane * D_);
    float row[D_];
    #pragma unroll
    for (int m = 0; m < D_ / 4; ++m) {
        float4 t = srow[m];
        row[4 * m + 0] = t.x; row[4 * m + 1] = t.y;
        row[4 * m + 2] = t.z; row[4 * m + 3] = t.w;
    }
    float d = x[bt * D_ + lane] - mu[bt * D_ + lane];

    float q = 0.f, lg = 0.f;
    #pragma unroll
    for (int g = 0; g < D_ / 4; ++g) {
        const int k0 = 4 * g;

        // --- 1. panel factor: columns k0..k0+3 (readlane only) ---
        #pragma unroll
        for (int p = 0; p < 4; ++p) {
            const int kp = k0 + p;
            // rank-p update of column kp from earlier panel columns
            #pragma unroll
            for (int pp = 0; pp < p; ++pp)
                row[kp] -= row[k0 + pp] * rl(row[k0 + pp], kp);
            float s   = rl(row[kp], kp) + 1e-6f;      // diag + EPS
            float inv = __builtin_amdgcn_rsqf(s);     // 1/L[kp][kp]
            lg += __builtin_amdgcn_logf(s);           // log2(s); scaled at end
            row[kp] *= inv;                           // a_p in place
            float zk = rl(d, kp) * inv;               // forward substitution
            q += zk * zk;
            d -= row[kp] * zk;                        // valid for lanes i > kp
        }

        if (g < D_ / 4 - 1) {
            // --- 2. publish the 4 scaled columns: one b128 write/lane ---
            float* cb = (g & 1) ? cb1 : cb0;
            *(v4f*)(cb + 4 * lane) =
                (v4f){row[k0], row[k0 + 1], row[k0 + 2], row[k0 + 3]};

            // --- 3. rank-4 trailing update, one b128 broadcast per col ---
            #pragma unroll
            for (int m = g + 1; m < D_ / 4; ++m) {
                #pragma unroll
                for (int jj = 0; jj < 4; ++jj) {
                    const int j = 4 * m + jj;
                    v4f b = *(const v4f*)(cb + 4 * j);   // L[j][k0..k0+3]
                    row[j] -= row[k0]     * b[0] + row[k0 + 1] * b[1]
                            + row[k0 + 2] * b[2] + row[k0 + 3] * b[3];
                }
            }
        }
    }

    if (lane == 0) {
        float log_det = 0.34657359027997264f * lg;      // 0.5 * ln(2) * sum(log2 s)
        // -0.5*sum(z^2) - log_det - 0.5*D*ln(2*pi)
        float lp = -0.5f * q - log_det - 58.81206612509905f;
        partial[bt] = lp;
    }
}

__global__ __launch_bounds__(1024) void reduce_ll(const float* __restrict__ partial,
                                                  float* __restrict__ out) {
    float s = 0.f;
    for (int i = threadIdx.x; i < NBT_; i += 1024) s += partial[i];
    #pragma unroll
    for (int off = 32; off > 0; off >>= 1) s += __shfl_down(s, off, 64);
    __shared__ float ws[16];
    const int lane = threadIdx.x & 63, w = threadIdx.x >> 6;
    if (lane == 0) ws[w] = s;
    __syncthreads();
    if (threadIdx.x == 0) {
        float t = 0.f;
        #pragma unroll
        for (int i = 0; i < 16; ++i) t += ws[i];
        out[0] = -t / (float)B_;   // out = -mean_b sum_t log_prob
    }
}

extern "C" void kernel_launch(void* const* d_in, const int* in_sizes, int n_in,
                              void* d_out, int out_size, void* d_ws, size_t ws_size,
                              hipStream_t stream) {
    const float* x     = (const float*)d_in[0];
    const float* mu    = (const float*)d_in[1];
    const float* sigma = (const float*)d_in[2];
    float* partial = (float*)d_ws;   // NBT_ floats = 51.2 KB scratch
    chol_ll<<<NBT_ / 4, 256, 0, stream>>>(x, mu, sigma, partial);
    reduce_ll<<<1, 1024, 0, stream>>>(partial, (float*)d_out);
}